// Round 5
// baseline (186.334 us; speedup 1.0000x reference)
//
#include <hip/hip_runtime.h>
#include <float.h>
#include <math.h>

#define B_SZ   2048
#define D_DIM  256
#define P_DIM  4
#define N_TOT  4096        // 2*B
#define EPS_F  1e-8f
#define NB     2048        // 512*4: float4 scan ownership, conflict-free
#define BSCALE 512.0f      // tie-approx error ~1.3e-2 << 0.146 threshold
#define RPB    8           // rows per block in row_kernel

typedef short  s16x8 __attribute__((ext_vector_type(8)));
typedef float  f32x4 __attribute__((ext_vector_type(4)));

__device__ __forceinline__ void async_load16(const void* g, const void* l) {
    __builtin_amdgcn_global_load_lds(
        (const __attribute__((address_space(1))) unsigned int*)g,
        (__attribute__((address_space(3))) unsigned int*)l,
        16, 0, 0);
}

__device__ __forceinline__ unsigned short f2bf(float x) {
    unsigned int b = __float_as_uint(x);
    b += 0x7FFFu + ((b >> 16) & 1u);        // RNE
    return (unsigned short)(b >> 16);
}

// ---------------- Kernel A: row-normalize features -> bf16 ----------------
__global__ __launch_bounds__(64) void normalize_kernel(
    const float* __restrict__ z_i, const float* __restrict__ z_j,
    unsigned short* __restrict__ fb)
{
    int row  = blockIdx.x;
    int lane = threadIdx.x;
    const float* src = (row < B_SZ) ? (z_i + (size_t)row * D_DIM)
                                    : (z_j + (size_t)(row - B_SZ) * D_DIM);
    float4 v = ((const float4*)src)[lane];
    float ss = v.x*v.x + v.y*v.y + v.z*v.z + v.w*v.w;
    #pragma unroll
    for (int off = 32; off > 0; off >>= 1)
        ss += __shfl_down(ss, off, 64);
    ss = __shfl(ss, 0, 64);
    float inv = 1.0f / sqrtf(ss);
    ushort4 o;
    o.x = f2bf(v.x * inv); o.y = f2bf(v.y * inv);
    o.z = f2bf(v.z * inv); o.w = f2bf(v.w * inv);
    ((ushort4*)(fb + (size_t)row * D_DIM))[lane] = o;
}

// ---------------- Kernel B: logits = f @ f^T / TEMP (UNCHANGED from R4) ----------------
__global__ __launch_bounds__(256, 1) void gemm_kernel(
    const unsigned short* __restrict__ fb, unsigned short* __restrict__ out)
{
    __shared__ unsigned short AB[2][256 * 32];   // 2 x 16 KB; rows [0,128)=A, [128,256)=B

    int tid = threadIdx.x;
    int w   = tid >> 6;           // 4 waves
    int L   = tid & 63;
    int bm  = blockIdx.y * 128;
    int bn  = blockIdx.x * 128;

    f32x4 acc[4][4];
    #pragma unroll
    for (int r = 0; r < 4; ++r)
        #pragma unroll
        for (int c = 0; c < 4; ++c)
            #pragma unroll
            for (int q = 0; q < 4; ++q) acc[r][c][q] = 0.f;

    const int wr = (w >> 1) * 64;      // wave quadrant: 2x2 grid of 64x64
    const int wc = (w & 1) * 64;

    const int r_sub   = (L >> 2);
    const int k_src   = ((L & 3) ^ (r_sub & 3)) * 8;   // shorts

    #define STAGE(buf, k0)                                                        \
        {                                                                         \
            unsigned short* lb = AB[buf] + (w * 64) * 32;                         \
            _Pragma("unroll")                                                     \
            for (int c = 0; c < 4; ++c) {                                         \
                int r = w * 64 + c * 16 + r_sub;                                  \
                int grow = (r < 128) ? (bm + r) : (bn + r - 128);                 \
                async_load16(fb + (size_t)grow * D_DIM + (k0) + k_src,            \
                             lb + c * 512);                                       \
            }                                                                     \
        }

    STAGE(0, 0)
    __syncthreads();

    const int rslot = ((L >> 4) ^ (L & 3)) * 8;        // shorts

    int cur = 0;
    for (int k0 = 0; k0 < D_DIM; k0 += 32) {
        if (k0 + 32 < D_DIM) STAGE(cur ^ 1, k0 + 32)

        const unsigned short* buf = AB[cur];
        s16x8 a[4], b[4];
        #pragma unroll
        for (int rt = 0; rt < 4; ++rt)
            a[rt] = *(const s16x8*)(buf + (wr + rt * 16 + (L & 15)) * 32 + rslot);
        #pragma unroll
        for (int ct = 0; ct < 4; ++ct)
            b[ct] = *(const s16x8*)(buf + (128 + wc + ct * 16 + (L & 15)) * 32 + rslot);
        #pragma unroll
        for (int rt = 0; rt < 4; ++rt)
            #pragma unroll
            for (int ct = 0; ct < 4; ++ct)
                acc[rt][ct] = __builtin_amdgcn_mfma_f32_16x16x32_bf16(
                    a[rt], b[ct], acc[rt][ct], 0, 0, 0);

        __syncthreads();
        cur ^= 1;
    }

    #pragma unroll
    for (int rt = 0; rt < 4; ++rt) {
        #pragma unroll
        for (int ct = 0; ct < 4; ++ct) {
            int col = bn + wc + ct * 16 + (L & 15);
            #pragma unroll
            for (int q = 0; q < 4; ++q) {
                int row = bm + wr + rt * 16 + (L >> 4) * 4 + q;
                out[(size_t)row * N_TOT + col] = f2bf(acc[rt][ct][q] * 0.5f); // /TEMP
            }
        }
    }
}

// ---------------- Kernel C: 8 rows/block, all inner-loop data LDS/register-resident ----------------
// R0-R4 diagnosis: row was VMEM-gather-latency-bound (VALUBusy 18%, HBM 2%, 100us vs
// ~10us VALU floor); compiler refuses to pipeline the physics gathers (chooses VGPR
// 44/20). Fix: thread's 8 Lj label vecs are IDENTICAL across rows (strided j-ownership)
// -> load once per block into registers, amortize over 8 rows. Per-row logits (8KB)
// double-buffered in LDS via global_load_lds. Inner loop = registers + LDS only.
__global__ __launch_bounds__(512, 4) void row_kernel(
    const unsigned short* __restrict__ logits,
    const float* __restrict__ physics_i, const float* __restrict__ physics_j,
    float* __restrict__ rowres)
{
    __shared__ float hist[NB];                              // 8 KB
    __shared__ __align__(16) unsigned short Llog[2][N_TOT]; // 16 KB
    __shared__ float scr[8];

    int tid  = threadIdx.x;
    int lane = tid & 63;
    int wid  = tid >> 6;                     // 0..7
    int i0   = blockIdx.x * RPB;

    // one-time gather: this thread's 8 Lj label vectors (same j-set for every row)
    float4 Lj[8];
    #pragma unroll
    for (int t = 0; t < 8; ++t) {
        int j = tid + t * 512;
        const float* p = (j < B_SZ) ? (physics_i + (size_t)j * P_DIM)
                                    : (physics_j + (size_t)(j - B_SZ) * P_DIM);
        Lj[t] = *(const float4*)p;
    }

    // stage row 0 logits: 512 lanes x 16B = 8KB; wave-uniform LDS base + lane*16
    async_load16(logits + (size_t)i0 * N_TOT + tid * 8, Llog[0] + wid * 512);

    float LS = 0.f, SL = 0.f;                // deferred across rows

    for (int r = 0; r < RPB; ++r) {
        int i = i0 + r;
        __syncthreads();                     // buf[r&1] staged; prev phase3 done

        if (r + 1 < RPB)                     // stage next row into other buffer
            async_load16(logits + (size_t)(i + 1) * N_TOT + tid * 8,
                         Llog[(r + 1) & 1] + wid * 512);

        *(float4*)(hist + tid * 4) = float4{0.f, 0.f, 0.f, 0.f};

        const float* Lp = (i < B_SZ) ? (physics_i + (size_t)i * P_DIM)
                                     : (physics_j + (size_t)(i - B_SZ) * P_DIM);
        float4 Li = *(const float4*)Lp;      // uniform broadcast load
        __syncthreads();                     // zeros visible (also drains stage)

        // phase 1: registers + LDS only
        const unsigned short* lg = Llog[r & 1];
        int pb[8];
        #pragma unroll
        for (int t = 0; t < 8; ++t) {
            int j = tid + t * 512;
            float l = __uint_as_float((unsigned)lg[j] << 16);
            float d = fabsf(Li.x - Lj[t].x) + fabsf(Li.y - Lj[t].y)
                    + fabsf(Li.z - Lj[t].z) + fabsf(Li.w - Lj[t].w);
            int b = (int)(d * BSCALE); if (b > NB - 1) b = NB - 1;
            pb[t] = b;
            float e;
            if (j == i) e = 0.f; else { e = __expf(l); SL += l; }
            atomicAdd(&hist[b], e);
        }
        __syncthreads();                     // hist complete

        // suffix scan: thread owns hist[tid*4 .. +4) as float4
        float4 v = *(const float4*)(hist + tid * 4);
        float fs = v.x + v.y + v.z + v.w;
        float s = fs;
        #pragma unroll
        for (int off = 1; off < 64; off <<= 1) {
            float u = __shfl_down(s, off, 64);
            if (lane + off < 64) s += u;
        }
        if (lane == 0) scr[wid] = s;         // wave totals
        __syncthreads();
        float sb = 0.f;
        #pragma unroll
        for (int w2 = wid + 1; w2 < 8; ++w2) sb += scr[w2];
        float run = sb + s - fs;             // sum of buckets strictly above mine
        float4 o;
        o.w = run + v.w;
        o.z = o.w + v.z;
        o.y = o.z + v.y;
        o.x = o.y + v.x;
        *(float4*)(hist + tid * 4) = o;
        __syncthreads();                     // CDF ready

        // phase 3: denom lookups + logs (accumulate across rows)
        #pragma unroll
        for (int t = 0; t < 8; ++t) {
            int j = tid + t * 512;
            if (j != i) LS += __logf(hist[pb[t]] + EPS_F);
        }
    }

    // single block reduction of (LS - SL)
    float acc = LS - SL;
    #pragma unroll
    for (int off = 32; off > 0; off >>= 1)
        acc += __shfl_down(acc, off, 64);
    __syncthreads();                         // last row's scr use done
    if (lane == 0) scr[wid] = acc;
    __syncthreads();
    if (tid == 0) {
        float s = 0.f;
        #pragma unroll
        for (int w2 = 0; w2 < 8; ++w2) s += scr[w2];
        rowres[blockIdx.x] = s;              // block partial (8 rows)
    }
}

// ---------------- Kernel D: final reduce (512 block partials) ----------------
__global__ __launch_bounds__(256) void final_kernel(
    const float* __restrict__ rowres, float* __restrict__ out)
{
    __shared__ float red[4];
    int tid = threadIdx.x;
    float s = 0.f;
    for (int i = tid; i < N_TOT / RPB; i += 256) s += rowres[i];
    #pragma unroll
    for (int off = 32; off > 0; off >>= 1)
        s += __shfl_down(s, off, 64);
    if ((tid & 63) == 0) red[tid >> 6] = s;
    __syncthreads();
    if (tid == 0) {
        double tot = (double)red[0] + red[1] + red[2] + red[3];
        out[0] = (float)(tot / ((double)N_TOT * (N_TOT - 1)));
    }
}

extern "C" void kernel_launch(void* const* d_in, const int* in_sizes, int n_in,
                              void* d_out, int out_size, void* d_ws, size_t ws_size,
                              hipStream_t stream)
{
    const float* z_i  = (const float*)d_in[0];
    const float* z_j  = (const float*)d_in[1];
    const float* ph_i = (const float*)d_in[2];
    const float* ph_j = (const float*)d_in[3];

    unsigned short* fb     = (unsigned short*)d_ws;                        // 2 MB bf16
    unsigned short* logits = fb + (size_t)N_TOT * D_DIM;                   // 32 MB bf16
    float*          rowres = (float*)(logits + (size_t)N_TOT * N_TOT);     // 2 KB

    normalize_kernel<<<N_TOT, 64, 0, stream>>>(z_i, z_j, fb);
    dim3 g(N_TOT / 128, N_TOT / 128);
    gemm_kernel<<<g, 256, 0, stream>>>(fb, logits);
    row_kernel<<<N_TOT / RPB, 512, 0, stream>>>(logits, ph_i, ph_j, rowres);
    final_kernel<<<1, 256, 0, stream>>>(rowres, (float*)d_out);
}